// Round 10
// baseline (331.049 us; speedup 1.0000x reference)
//
#include <hip/hip_runtime.h>
#include <cstdint>
#include <math.h>

// Problem constants (from reference)
#define GRID_W 96
#define GRID_L 96
#define GRID_H 48
#define NVOX (GRID_W * GRID_L * GRID_H)   // 442368
#define VOXEL_SIZE 0.05f
#define MIN_PTS 10
#define BATCH 4
#define CHANS 16
#define NPTS (480 * 640)                  // 307200 points per batch
#define TOTPTS (BATCH * NPTS)             // 1228800
#define TOTVOX (BATCH * NVOX)             // 1769472

// Scan geometry: 864 blocks x 256 threads x 8 elems = 1769472 exactly.
#define SCAN_BLKS 864
#define SCAN_TPB 256
#define SCAN_EPT 8
#define SCAN_CHUNK (SCAN_TPB * SCAN_EPT)  // 2048

#define ROWW 8   // uint words per bf16 row (16 channels x 2B = 32B)

// Native vector types for __builtin_nontemporal_{load,store}.
typedef unsigned nt_uint4  __attribute__((ext_vector_type(4)));
typedef float    nt_float4 __attribute__((ext_vector_type(4)));
typedef float    nt_float2 __attribute__((ext_vector_type(2)));

// ---- workspace layout (bytes) ----
// offsets doubles as the count buffer (scan runs in-place).
#define WS_OFFSETS 0
#define WS_VR      ((TOTVOX + 4) * 4)                     //  7,077,904
#define WS_IDS     (WS_VR + TOTPTS * 4)                   // 11,993,104
#define WS_ROWS    (WS_IDS + TOTPTS * 4 + 16)             // 16,908,320 (32B aligned)
#define WS_SUMS    (WS_ROWS + (size_t)TOTPTS * ROWW * 4)  // 56,229,920
#define WS_NEEDED  ((size_t)(WS_SUMS + 4096))             // ~56.2 MB (< proven 90.6 MB budget)

// bf16 round-to-nearest-even (inputs finite)
__device__ __forceinline__ unsigned bf16_rtne(float f) {
    unsigned u = __float_as_uint(f);
    return (u + 0x7FFFu + ((u >> 16) & 1u)) >> 16;
}
__device__ __forceinline__ unsigned pack2(float lo, float hi) {
    return bf16_rtne(lo) | (bf16_rtne(hi) << 16);
}

// ============================== fast path ==============================

// Fused: per-point voxel id + histogram + POINT-ORDER bf16 row packing.
// TWO points per thread: the thread's rows write is a full 64 B line of
// REGULAR stores (L2 write-combines -> no NT 16B-granule amplification).
// Input streams (coords/attrs) use nontemporal LOADS: single-use, evict-
// first, keeping L2 room for the hot ~430 KB cnt atomic working set.
__global__ void k_hist_pack(const float* __restrict__ coords,   // [B,3,NPTS]
                            const float* __restrict__ attrs,    // [B,C,NPTS]
                            const float* __restrict__ origin,   // [B,3]
                            unsigned*    __restrict__ vr,       // [TOTPTS] packed
                            unsigned*    __restrict__ rows,     // [TOTPTS,8] words, point order
                            unsigned*    __restrict__ cnt)      // [TOTVOX] (= offsets buf)
{
    int t = blockIdx.x * blockDim.x + threadIdx.x;
    if (t >= TOTPTS / 2) return;
    int pid = t * 2;
    int b = pid / NPTS;          // NPTS % 2 == 0 -> both points same batch
    int n = pid - b * NPTS;

    const float* cb = coords + (size_t)b * 3 * NPTS;
    nt_float2 X = __builtin_nontemporal_load((const nt_float2*)(cb + n));
    nt_float2 Y = __builtin_nontemporal_load((const nt_float2*)(cb + NPTS + n));
    nt_float2 Z = __builtin_nontemporal_load((const nt_float2*)(cb + 2 * NPTS + n));
    float ox = origin[b * 3 + 0];
    float oy = origin[b * 3 + 1];
    float oz = origin[b * 3 + 2];

    // Pack both points' 16 channels to bf16 rows (64 B contiguous/thread).
    const float* ab = attrs + (size_t)b * CHANS * NPTS + n;
    unsigned w[2][ROWW];
    #pragma unroll
    for (int c = 0; c < CHANS; c += 2) {
        nt_float2 a0 = __builtin_nontemporal_load((const nt_float2*)(ab + (size_t)c * NPTS));
        nt_float2 a1 = __builtin_nontemporal_load((const nt_float2*)(ab + (size_t)(c + 1) * NPTS));
        w[0][c >> 1] = pack2(a0.x, a1.x);
        w[1][c >> 1] = pack2(a0.y, a1.y);
    }
    uint4* dst = (uint4*)(rows + (size_t)pid * ROWW);
    dst[0] = uint4{w[0][0], w[0][1], w[0][2], w[0][3]};
    dst[1] = uint4{w[0][4], w[0][5], w[0][6], w[0][7]};
    dst[2] = uint4{w[1][0], w[1][1], w[1][2], w[1][3]};
    dst[3] = uint4{w[1][4], w[1][5], w[1][6], w[1][7]};

    // IEEE f32 division + floorf: must match numpy reference binning exactly.
    float xs[2] = {X.x, X.y};
    float ys[2] = {Y.x, Y.y};
    float zs[2] = {Z.x, Z.y};
    unsigned ps[2];
    #pragma unroll
    for (int k = 0; k < 2; ++k) {
        int ix = (int)floorf((xs[k] - ox) / VOXEL_SIZE);
        int iy = (int)floorf((ys[k] - oy) / VOXEL_SIZE);
        int iz = (int)floorf((zs[k] - oz) / VOXEL_SIZE);
        unsigned p = 0xFFFFFFFFu;
        if ((unsigned)ix < GRID_W && (unsigned)iy < GRID_L && (unsigned)iz < GRID_H) {
            int v = b * NVOX + ix * (GRID_L * GRID_H) + iy * GRID_H + iz;
            unsigned r = atomicAdd(&cnt[v], 1u);
            p = ((unsigned)v << 10) | (r & 1023u);
        }
        ps[k] = p;
    }
    *(uint2*)(vr + pid) = uint2{ps[0], ps[1]};
}

// Scan level 1, IN-PLACE on the count buffer: per-2048-chunk exclusive
// partials + chunk totals. Also emits the occupancy output plane.
__global__ void k_scan1(unsigned* __restrict__ offsets,   // counts in, partial offsets out
                        unsigned* __restrict__ sums,
                        float*    __restrict__ occ)       // [TOTVOX] in d_out
{
    __shared__ unsigned s[SCAN_TPB];
    int t = threadIdx.x;
    int base = blockIdx.x * SCAN_CHUNK + t * SCAN_EPT;

    uint4 a = ((const uint4*)(offsets + base))[0];
    uint4 c = ((const uint4*)(offsets + base))[1];
    unsigned e[SCAN_EPT] = {a.x, a.y, a.z, a.w, c.x, c.y, c.z, c.w};

    nt_float4 oc0, oc1;
    oc0.x = (e[0] >= MIN_PTS) ? 1.f : 0.f;  oc0.y = (e[1] >= MIN_PTS) ? 1.f : 0.f;
    oc0.z = (e[2] >= MIN_PTS) ? 1.f : 0.f;  oc0.w = (e[3] >= MIN_PTS) ? 1.f : 0.f;
    oc1.x = (e[4] >= MIN_PTS) ? 1.f : 0.f;  oc1.y = (e[5] >= MIN_PTS) ? 1.f : 0.f;
    oc1.z = (e[6] >= MIN_PTS) ? 1.f : 0.f;  oc1.w = (e[7] >= MIN_PTS) ? 1.f : 0.f;
    __builtin_nontemporal_store(oc0, ((nt_float4*)(occ + base)));
    __builtin_nontemporal_store(oc1, ((nt_float4*)(occ + base)) + 1);

    unsigned tot = 0;
    #pragma unroll
    for (int k = 0; k < SCAN_EPT; ++k) { unsigned v = e[k]; e[k] = tot; tot += v; }

    s[t] = tot;
    __syncthreads();
    #pragma unroll
    for (int off = 1; off < SCAN_TPB; off <<= 1) {
        unsigned v = (t >= off) ? s[t - off] : 0u;
        __syncthreads();
        s[t] += v;
        __syncthreads();
    }
    unsigned prefix = s[t] - tot;   // exclusive within chunk
    #pragma unroll
    for (int k = 0; k < SCAN_EPT; ++k) e[k] += prefix;

    ((uint4*)(offsets + base))[0] = uint4{e[0], e[1], e[2], e[3]};
    ((uint4*)(offsets + base))[1] = uint4{e[4], e[5], e[6], e[7]};

    if (t == SCAN_TPB - 1) sums[blockIdx.x] = s[t];
}

// Scan level 2: exclusive scan of the 864 chunk sums (single block).
// Consumers add sums[v >> 11] themselves. sums[SCAN_BLKS] = grand total.
__global__ void k_scan2(unsigned* __restrict__ sums) {
    __shared__ unsigned s[1024];
    int t = threadIdx.x;
    unsigned my = (t < SCAN_BLKS) ? sums[t] : 0u;
    s[t] = my;
    __syncthreads();
    #pragma unroll
    for (int off = 1; off < 1024; off <<= 1) {
        unsigned v = (t >= off) ? s[t - off] : 0u;
        __syncthreads();
        s[t] += v;
        __syncthreads();
    }
    if (t < SCAN_BLKS) sums[t] = s[t] - my;          // exclusive
    if (t == SCAN_BLKS - 1) sums[SCAN_BLKS] = s[t];  // grand total sentinel
}

// Scatter point-ids into voxel segments. The random 4 B writes land in a
// 4.9 MB array -> fully absorbed by the 32 MB aggregate L2. No atomics.
__global__ void k_scatter_ids4(const unsigned* __restrict__ vr,      // [TOTPTS] packed
                               const unsigned* __restrict__ offsets, // [TOTVOX]
                               const unsigned* __restrict__ sums,    // [SCAN_BLKS+1]
                               int*            __restrict__ ids)     // [TOTPTS]
{
    int t = blockIdx.x * blockDim.x + threadIdx.x;
    if (t >= TOTPTS / 4) return;
    int pid = t * 4;
    uint4 P = *(const uint4*)(vr + pid);
    unsigned ps[4] = {P.x, P.y, P.z, P.w};
    #pragma unroll
    for (int k = 0; k < 4; ++k) {
        if (ps[k] != 0xFFFFFFFFu) {
            unsigned v = ps[k] >> 10;
            unsigned pos = offsets[v] + sums[v >> 11] + (ps[k] & 1023u);
            ids[pos] = pid + k;
        }
    }
}

// Gather + finalize: ONE thread per 2 adjacent voxels, all 16 channels.
// Sequential ids reads; random 32 B row reads via nontemporal loads
// (single-use stream, evict-first). j-loop unrolled x2 (4 row-loads
// outstanding). Nontemporal float2 output stores (full-line dirty/wave).
__global__ void k_gather_ind2(const unsigned* __restrict__ rows,    // [TOTPTS,8] point order
                              const int*      __restrict__ ids,     // [TOTPTS]
                              const unsigned* __restrict__ offsets, // [TOTVOX+4]
                              const unsigned* __restrict__ sums,    // [SCAN_BLKS+1]
                              float*          __restrict__ data)    // [B,C,NVOX]
{
    int g = blockIdx.x * blockDim.x + threadIdx.x;
    if (g >= TOTVOX / 2) return;
    int vox0 = g * 2;

    // vox0 % 2 == 0 and chunk size 2048 % 2 == 0 -> vox0, vox0+1 same chunk.
    uint2 O = *(const uint2*)(offsets + vox0);
    unsigned base = sums[vox0 >> 11];
    unsigned s[3];
    s[0] = O.x + base;
    s[1] = O.y + base;
    s[2] = offsets[vox0 + 2] + sums[(vox0 + 2) >> 11];  // sentinels cover end

    float m[2][CHANS];
    #pragma unroll
    for (int q = 0; q < 2; ++q) {
        unsigned k = s[q + 1] - s[q];
        unsigned s0 = s[q];
        if (k >= MIN_PTS) {
            const float ninf = -__builtin_inff();
            #pragma unroll
            for (int c = 0; c < CHANS; ++c) m[q][c] = ninf;
            unsigned j = 0;
            for (; j + 2 <= k; j += 2) {           // unroll x2 for MLP
                int p0 = ids[s0 + j];
                int p1 = ids[s0 + j + 1];
                const nt_uint4* r0p = (const nt_uint4*)(rows + (size_t)p0 * ROWW);
                const nt_uint4* r1p = (const nt_uint4*)(rows + (size_t)p1 * ROWW);
                nt_uint4 l0 = __builtin_nontemporal_load(r0p);
                nt_uint4 h0 = __builtin_nontemporal_load(r0p + 1);
                nt_uint4 l1 = __builtin_nontemporal_load(r1p);
                nt_uint4 h1 = __builtin_nontemporal_load(r1p + 1);
                unsigned wa[8] = {l0.x, l0.y, l0.z, l0.w, h0.x, h0.y, h0.z, h0.w};
                unsigned wb[8] = {l1.x, l1.y, l1.z, l1.w, h1.x, h1.y, h1.z, h1.w};
                #pragma unroll
                for (int h = 0; h < 8; ++h) {
                    m[q][2 * h]     = fmaxf(m[q][2 * h],
                                        fmaxf(__uint_as_float(wa[h] << 16),
                                              __uint_as_float(wb[h] << 16)));
                    m[q][2 * h + 1] = fmaxf(m[q][2 * h + 1],
                                        fmaxf(__uint_as_float(wa[h] & 0xFFFF0000u),
                                              __uint_as_float(wb[h] & 0xFFFF0000u)));
                }
            }
            if (j < k) {
                int p0 = ids[s0 + j];
                const nt_uint4* r0p = (const nt_uint4*)(rows + (size_t)p0 * ROWW);
                nt_uint4 l0 = __builtin_nontemporal_load(r0p);
                nt_uint4 h0 = __builtin_nontemporal_load(r0p + 1);
                unsigned wa[8] = {l0.x, l0.y, l0.z, l0.w, h0.x, h0.y, h0.z, h0.w};
                #pragma unroll
                for (int h = 0; h < 8; ++h) {
                    m[q][2 * h]     = fmaxf(m[q][2 * h], __uint_as_float(wa[h] << 16));
                    m[q][2 * h + 1] = fmaxf(m[q][2 * h + 1],
                                            __uint_as_float(wa[h] & 0xFFFF0000u));
                }
            }
            #pragma unroll
            for (int c = 0; c < CHANS; ++c) if (!isfinite(m[q][c])) m[q][c] = 0.f;
        } else {
            #pragma unroll
            for (int c = 0; c < CHANS; ++c) m[q][c] = 0.f;
        }
    }

    int b = vox0 / NVOX;                 // NVOX % 2 == 0
    int v0 = vox0 - b * NVOX;
    float* db = data + (size_t)b * CHANS * NVOX + v0;
    #pragma unroll
    for (int c = 0; c < CHANS; ++c) {
        nt_float2 o = {m[0][c], m[1][c]};
        __builtin_nontemporal_store(o, (nt_float2*)(db + (size_t)c * NVOX));
    }
}

// ============================== fallback path (round-1) ==============================

__device__ __forceinline__ unsigned flip_f32(float f) {
    unsigned u = __float_as_uint(f);
    unsigned mask = (unsigned)(-(int)(u >> 31)) | 0x80000000u;
    return u ^ mask;
}
__device__ __forceinline__ float unflip_f32(unsigned u) {
    unsigned mask = ((u >> 31) - 1u) | 0x80000000u;
    return __uint_as_float(u ^ mask);
}
#define FLIP_NEG_INF 0x007FFFFFu

__global__ void pv_init(uint4* __restrict__ out) {
    const int DATA4 = BATCH * CHANS * NVOX / 4;
    const int TOT4  = BATCH * (CHANS + 1) * NVOX / 4;
    int i = blockIdx.x * blockDim.x + threadIdx.x;
    if (i < TOT4) {
        unsigned val = (i < DATA4) ? FLIP_NEG_INF : 0u;
        out[i] = uint4{val, val, val, val};
    }
}

__global__ void pv_scatter(const float* __restrict__ coords,
                           const float* __restrict__ attrs,
                           const float* __restrict__ origin,
                           unsigned*    __restrict__ data_u,
                           unsigned*    __restrict__ cnt)
{
    int id = blockIdx.x * blockDim.x + threadIdx.x;
    if (id >= TOTPTS) return;
    int b = id / NPTS;
    int n = id - b * NPTS;
    const float* cb = coords + (size_t)b * 3 * NPTS;
    float x = cb[n], y = cb[NPTS + n], z = cb[2 * NPTS + n];
    float ox = origin[b * 3 + 0], oy = origin[b * 3 + 1], oz = origin[b * 3 + 2];
    int ix = (int)floorf((x - ox) / VOXEL_SIZE);
    int iy = (int)floorf((y - oy) / VOXEL_SIZE);
    int iz = (int)floorf((z - oz) / VOXEL_SIZE);
    if ((unsigned)ix < GRID_W && (unsigned)iy < GRID_L && (unsigned)iz < GRID_H) {
        int flat = ix * (GRID_L * GRID_H) + iy * GRID_H + iz;
        atomicAdd(&cnt[b * NVOX + flat], 1u);
        const float* ab = attrs + (size_t)b * CHANS * NPTS + n;
        unsigned*    db = data_u + (size_t)b * CHANS * NVOX + flat;
        #pragma unroll
        for (int c = 0; c < CHANS; ++c)
            atomicMax(&db[(size_t)c * NVOX], flip_f32(ab[(size_t)c * NPTS]));
    }
}

__global__ void pv_finalize(unsigned* __restrict__ data_u,
                            unsigned* __restrict__ cnt_u)
{
    int id = blockIdx.x * blockDim.x + threadIdx.x;
    if (id >= TOTVOX) return;
    int b = id / NVOX;
    int v = id - b * NVOX;
    unsigned cnt = cnt_u[id];
    bool occ = (cnt >= MIN_PTS);
    ((float*)cnt_u)[id] = occ ? 1.0f : 0.0f;
    unsigned* db = data_u + (size_t)b * CHANS * NVOX + v;
    #pragma unroll
    for (int c = 0; c < CHANS; ++c) {
        float f = unflip_f32(db[(size_t)c * NVOX]);
        ((float*)db)[(size_t)c * NVOX] = (occ && isfinite(f)) ? f : 0.0f;
    }
}

// ============================== launch ==============================

extern "C" void kernel_launch(void* const* d_in, const int* in_sizes, int n_in,
                              void* d_out, int out_size, void* d_ws, size_t ws_size,
                              hipStream_t stream) {
    const float* coords = (const float*)d_in[0];  // [4,3,480,640]
    const float* attrs  = (const float*)d_in[1];  // [4,16,480,640]
    const float* origin = (const float*)d_in[2];  // [4,3]

    float* out = (float*)d_out;
    float* data = out;                                          // [B,C,NVOX]
    float* occ  = out + (size_t)BATCH * CHANS * NVOX;           // [B,NVOX]

    if (ws_size >= WS_NEEDED) {
        char* ws = (char*)d_ws;
        unsigned* offsets = (unsigned*)(ws + WS_OFFSETS);  // counts -> offsets (in-place)
        unsigned* vr      = (unsigned*)(ws + WS_VR);
        int*      ids     = (int*)(ws + WS_IDS);
        unsigned* rows    = (unsigned*)(ws + WS_ROWS);
        unsigned* sums    = (unsigned*)(ws + WS_SUMS);

        // zero counts + the 4 sentinel words past the end
        (void)hipMemsetAsync(offsets, 0, (size_t)(TOTVOX + 4) * 4, stream);
        k_hist_pack<<<(TOTPTS / 2 + 255) / 256, 256, 0, stream>>>(coords, attrs, origin,
                                                                  vr, rows, offsets);
        k_scan1<<<SCAN_BLKS, SCAN_TPB, 0, stream>>>(offsets, sums, occ);
        k_scan2<<<1, 1024, 0, stream>>>(sums);
        k_scatter_ids4<<<(TOTPTS / 4 + 255) / 256, 256, 0, stream>>>(vr, offsets, sums, ids);
        k_gather_ind2<<<(TOTVOX / 2 + 255) / 256, 256, 0, stream>>>(rows, ids, offsets, sums, data);
    } else {
        unsigned* data_u = (unsigned*)data;
        unsigned* cnt    = (unsigned*)occ;
        const int TOT4 = BATCH * (CHANS + 1) * NVOX / 4;
        pv_init<<<(TOT4 + 255) / 256, 256, 0, stream>>>((uint4*)d_out);
        pv_scatter<<<(TOTPTS + 255) / 256, 256, 0, stream>>>(coords, attrs, origin, data_u, cnt);
        pv_finalize<<<(TOTVOX + 255) / 256, 256, 0, stream>>>(data_u, cnt);
    }
}

// Round 11
// 285.940 us; speedup vs baseline: 1.1578x; 1.1578x over previous
//
#include <hip/hip_runtime.h>
#include <cstdint>
#include <math.h>

// Problem constants (from reference)
#define GRID_W 96
#define GRID_L 96
#define GRID_H 48
#define NVOX (GRID_W * GRID_L * GRID_H)   // 442368
#define VOXEL_SIZE 0.05f
#define MIN_PTS 10
#define BATCH 4
#define CHANS 16
#define NPTS (480 * 640)                  // 307200 points per batch
#define TOTPTS (BATCH * NPTS)             // 1228800
#define TOTVOX (BATCH * NVOX)             // 1769472

// Scan geometry: 864 blocks x 256 threads x 8 elems = 1769472 exactly.
#define SCAN_BLKS 864
#define SCAN_TPB 256
#define SCAN_EPT 8
#define SCAN_CHUNK (SCAN_TPB * SCAN_EPT)  // 2048

#define ROWW 8   // uint words per bf16 row (16 channels x 2B = 32B)

// Native vector types for __builtin_nontemporal_{load,store}.
typedef unsigned nt_uint4  __attribute__((ext_vector_type(4)));
typedef float    nt_float4 __attribute__((ext_vector_type(4)));
typedef float    nt_float2 __attribute__((ext_vector_type(2)));

// ---- workspace layout (bytes) ----
// offsets doubles as the count buffer (scan runs in-place).
#define WS_OFFSETS 0
#define WS_VR      ((TOTVOX + 4) * 4)                     //  7,077,904
#define WS_IDS     (WS_VR + TOTPTS * 4)                   // 11,993,104
#define WS_ROWS    (WS_IDS + TOTPTS * 4 + 16)             // 16,908,320 (32B aligned)
#define WS_SUMS    (WS_ROWS + (size_t)TOTPTS * ROWW * 4)  // 56,229,920
#define WS_NEEDED  ((size_t)(WS_SUMS + 4096))             // ~56.2 MB (< proven 90.6 MB budget)

// bf16 round-to-nearest-even (inputs finite)
__device__ __forceinline__ unsigned bf16_rtne(float f) {
    unsigned u = __float_as_uint(f);
    return (u + 0x7FFFu + ((u >> 16) & 1u)) >> 16;
}
__device__ __forceinline__ unsigned pack2(float lo, float hi) {
    return bf16_rtne(lo) | (bf16_rtne(hi) << 16);
}

// ============================== fast path ==============================

// Fused: per-point voxel id + histogram + POINT-ORDER bf16 row packing.
// TWO points per thread: the thread's rows write is a full 64 B line of
// REGULAR stores (L2 write-combines -> no NT 16B-granule amplification).
// Input streams (coords/attrs) use nontemporal LOADS: single-use, evict-
// first, keeping L2 room for the hot ~430 KB cnt atomic working set.
__global__ void k_hist_pack(const float* __restrict__ coords,   // [B,3,NPTS]
                            const float* __restrict__ attrs,    // [B,C,NPTS]
                            const float* __restrict__ origin,   // [B,3]
                            unsigned*    __restrict__ vr,       // [TOTPTS] packed
                            unsigned*    __restrict__ rows,     // [TOTPTS,8] words, point order
                            unsigned*    __restrict__ cnt)      // [TOTVOX] (= offsets buf)
{
    int t = blockIdx.x * blockDim.x + threadIdx.x;
    if (t >= TOTPTS / 2) return;
    int pid = t * 2;
    int b = pid / NPTS;          // NPTS % 2 == 0 -> both points same batch
    int n = pid - b * NPTS;

    const float* cb = coords + (size_t)b * 3 * NPTS;
    nt_float2 X = __builtin_nontemporal_load((const nt_float2*)(cb + n));
    nt_float2 Y = __builtin_nontemporal_load((const nt_float2*)(cb + NPTS + n));
    nt_float2 Z = __builtin_nontemporal_load((const nt_float2*)(cb + 2 * NPTS + n));
    float ox = origin[b * 3 + 0];
    float oy = origin[b * 3 + 1];
    float oz = origin[b * 3 + 2];

    // Pack both points' 16 channels to bf16 rows (64 B contiguous/thread).
    const float* ab = attrs + (size_t)b * CHANS * NPTS + n;
    unsigned w[2][ROWW];
    #pragma unroll
    for (int c = 0; c < CHANS; c += 2) {
        nt_float2 a0 = __builtin_nontemporal_load((const nt_float2*)(ab + (size_t)c * NPTS));
        nt_float2 a1 = __builtin_nontemporal_load((const nt_float2*)(ab + (size_t)(c + 1) * NPTS));
        w[0][c >> 1] = pack2(a0.x, a1.x);
        w[1][c >> 1] = pack2(a0.y, a1.y);
    }
    uint4* dst = (uint4*)(rows + (size_t)pid * ROWW);
    dst[0] = uint4{w[0][0], w[0][1], w[0][2], w[0][3]};
    dst[1] = uint4{w[0][4], w[0][5], w[0][6], w[0][7]};
    dst[2] = uint4{w[1][0], w[1][1], w[1][2], w[1][3]};
    dst[3] = uint4{w[1][4], w[1][5], w[1][6], w[1][7]};

    // IEEE f32 division + floorf: must match numpy reference binning exactly.
    float xs[2] = {X.x, X.y};
    float ys[2] = {Y.x, Y.y};
    float zs[2] = {Z.x, Z.y};
    unsigned ps[2];
    #pragma unroll
    for (int k = 0; k < 2; ++k) {
        int ix = (int)floorf((xs[k] - ox) / VOXEL_SIZE);
        int iy = (int)floorf((ys[k] - oy) / VOXEL_SIZE);
        int iz = (int)floorf((zs[k] - oz) / VOXEL_SIZE);
        unsigned p = 0xFFFFFFFFu;
        if ((unsigned)ix < GRID_W && (unsigned)iy < GRID_L && (unsigned)iz < GRID_H) {
            int v = b * NVOX + ix * (GRID_L * GRID_H) + iy * GRID_H + iz;
            unsigned r = atomicAdd(&cnt[v], 1u);
            p = ((unsigned)v << 10) | (r & 1023u);
        }
        ps[k] = p;
    }
    *(uint2*)(vr + pid) = uint2{ps[0], ps[1]};
}

// Scan level 1, IN-PLACE on the count buffer: per-2048-chunk exclusive
// partials + chunk totals. Also emits the occupancy output plane.
__global__ void k_scan1(unsigned* __restrict__ offsets,   // counts in, partial offsets out
                        unsigned* __restrict__ sums,
                        float*    __restrict__ occ)       // [TOTVOX] in d_out
{
    __shared__ unsigned s[SCAN_TPB];
    int t = threadIdx.x;
    int base = blockIdx.x * SCAN_CHUNK + t * SCAN_EPT;

    uint4 a = ((const uint4*)(offsets + base))[0];
    uint4 c = ((const uint4*)(offsets + base))[1];
    unsigned e[SCAN_EPT] = {a.x, a.y, a.z, a.w, c.x, c.y, c.z, c.w};

    nt_float4 oc0, oc1;
    oc0.x = (e[0] >= MIN_PTS) ? 1.f : 0.f;  oc0.y = (e[1] >= MIN_PTS) ? 1.f : 0.f;
    oc0.z = (e[2] >= MIN_PTS) ? 1.f : 0.f;  oc0.w = (e[3] >= MIN_PTS) ? 1.f : 0.f;
    oc1.x = (e[4] >= MIN_PTS) ? 1.f : 0.f;  oc1.y = (e[5] >= MIN_PTS) ? 1.f : 0.f;
    oc1.z = (e[6] >= MIN_PTS) ? 1.f : 0.f;  oc1.w = (e[7] >= MIN_PTS) ? 1.f : 0.f;
    __builtin_nontemporal_store(oc0, ((nt_float4*)(occ + base)));
    __builtin_nontemporal_store(oc1, ((nt_float4*)(occ + base)) + 1);

    unsigned tot = 0;
    #pragma unroll
    for (int k = 0; k < SCAN_EPT; ++k) { unsigned v = e[k]; e[k] = tot; tot += v; }

    s[t] = tot;
    __syncthreads();
    #pragma unroll
    for (int off = 1; off < SCAN_TPB; off <<= 1) {
        unsigned v = (t >= off) ? s[t - off] : 0u;
        __syncthreads();
        s[t] += v;
        __syncthreads();
    }
    unsigned prefix = s[t] - tot;   // exclusive within chunk
    #pragma unroll
    for (int k = 0; k < SCAN_EPT; ++k) e[k] += prefix;

    ((uint4*)(offsets + base))[0] = uint4{e[0], e[1], e[2], e[3]};
    ((uint4*)(offsets + base))[1] = uint4{e[4], e[5], e[6], e[7]};

    if (t == SCAN_TPB - 1) sums[blockIdx.x] = s[t];
}

// Scan level 2: exclusive scan of the 864 chunk sums (single block).
// Consumers add sums[v >> 11] themselves. sums[SCAN_BLKS] = grand total.
__global__ void k_scan2(unsigned* __restrict__ sums) {
    __shared__ unsigned s[1024];
    int t = threadIdx.x;
    unsigned my = (t < SCAN_BLKS) ? sums[t] : 0u;
    s[t] = my;
    __syncthreads();
    #pragma unroll
    for (int off = 1; off < 1024; off <<= 1) {
        unsigned v = (t >= off) ? s[t - off] : 0u;
        __syncthreads();
        s[t] += v;
        __syncthreads();
    }
    if (t < SCAN_BLKS) sums[t] = s[t] - my;          // exclusive
    if (t == SCAN_BLKS - 1) sums[SCAN_BLKS] = s[t];  // grand total sentinel
}

// Scatter point-ids into voxel segments. The random 4 B writes land in a
// 4.9 MB array -> fully absorbed by the 32 MB aggregate L2. No atomics.
__global__ void k_scatter_ids4(const unsigned* __restrict__ vr,      // [TOTPTS] packed
                               const unsigned* __restrict__ offsets, // [TOTVOX]
                               const unsigned* __restrict__ sums,    // [SCAN_BLKS+1]
                               int*            __restrict__ ids)     // [TOTPTS]
{
    int t = blockIdx.x * blockDim.x + threadIdx.x;
    if (t >= TOTPTS / 4) return;
    int pid = t * 4;
    uint4 P = *(const uint4*)(vr + pid);
    unsigned ps[4] = {P.x, P.y, P.z, P.w};
    #pragma unroll
    for (int k = 0; k < 4; ++k) {
        if (ps[k] != 0xFFFFFFFFu) {
            unsigned v = ps[k] >> 10;
            unsigned pos = offsets[v] + sums[v >> 11] + (ps[k] & 1023u);
            ids[pos] = pid + k;
        }
    }
}

// Gather + finalize: ONE thread per 2 adjacent voxels, all 16 channels.
// Sequential ids reads; random 32 B row reads use REGULAR cached loads
// (the 64 B line holding two adjacent rows is usually re-hit -> caching
// halves fetch vs NT; round-10 NT-load experiment: FETCH 40->67 MB, dur
// +25 us). j-loop unrolled x2 (4 row-loads outstanding). Nontemporal
// float2 output stores only (full-line dirty per wave, single-use).
__global__ void k_gather_ind2(const unsigned* __restrict__ rows,    // [TOTPTS,8] point order
                              const int*      __restrict__ ids,     // [TOTPTS]
                              const unsigned* __restrict__ offsets, // [TOTVOX+4]
                              const unsigned* __restrict__ sums,    // [SCAN_BLKS+1]
                              float*          __restrict__ data)    // [B,C,NVOX]
{
    int g = blockIdx.x * blockDim.x + threadIdx.x;
    if (g >= TOTVOX / 2) return;
    int vox0 = g * 2;

    // vox0 % 2 == 0 and chunk size 2048 % 2 == 0 -> vox0, vox0+1 same chunk.
    uint2 O = *(const uint2*)(offsets + vox0);
    unsigned base = sums[vox0 >> 11];
    unsigned s[3];
    s[0] = O.x + base;
    s[1] = O.y + base;
    s[2] = offsets[vox0 + 2] + sums[(vox0 + 2) >> 11];  // sentinels cover end

    float m[2][CHANS];
    #pragma unroll
    for (int q = 0; q < 2; ++q) {
        unsigned k = s[q + 1] - s[q];
        unsigned s0 = s[q];
        if (k >= MIN_PTS) {
            const float ninf = -__builtin_inff();
            #pragma unroll
            for (int c = 0; c < CHANS; ++c) m[q][c] = ninf;
            unsigned j = 0;
            for (; j + 2 <= k; j += 2) {           // unroll x2 for MLP
                int p0 = ids[s0 + j];
                int p1 = ids[s0 + j + 1];
                const uint4* r0p = (const uint4*)(rows + (size_t)p0 * ROWW);
                const uint4* r1p = (const uint4*)(rows + (size_t)p1 * ROWW);
                uint4 l0 = r0p[0], h0 = r0p[1];
                uint4 l1 = r1p[0], h1 = r1p[1];
                unsigned wa[8] = {l0.x, l0.y, l0.z, l0.w, h0.x, h0.y, h0.z, h0.w};
                unsigned wb[8] = {l1.x, l1.y, l1.z, l1.w, h1.x, h1.y, h1.z, h1.w};
                #pragma unroll
                for (int h = 0; h < 8; ++h) {
                    m[q][2 * h]     = fmaxf(m[q][2 * h],
                                        fmaxf(__uint_as_float(wa[h] << 16),
                                              __uint_as_float(wb[h] << 16)));
                    m[q][2 * h + 1] = fmaxf(m[q][2 * h + 1],
                                        fmaxf(__uint_as_float(wa[h] & 0xFFFF0000u),
                                              __uint_as_float(wb[h] & 0xFFFF0000u)));
                }
            }
            if (j < k) {
                int p0 = ids[s0 + j];
                const uint4* r0p = (const uint4*)(rows + (size_t)p0 * ROWW);
                uint4 l0 = r0p[0], h0 = r0p[1];
                unsigned wa[8] = {l0.x, l0.y, l0.z, l0.w, h0.x, h0.y, h0.z, h0.w};
                #pragma unroll
                for (int h = 0; h < 8; ++h) {
                    m[q][2 * h]     = fmaxf(m[q][2 * h], __uint_as_float(wa[h] << 16));
                    m[q][2 * h + 1] = fmaxf(m[q][2 * h + 1],
                                            __uint_as_float(wa[h] & 0xFFFF0000u));
                }
            }
            #pragma unroll
            for (int c = 0; c < CHANS; ++c) if (!isfinite(m[q][c])) m[q][c] = 0.f;
        } else {
            #pragma unroll
            for (int c = 0; c < CHANS; ++c) m[q][c] = 0.f;
        }
    }

    int b = vox0 / NVOX;                 // NVOX % 2 == 0
    int v0 = vox0 - b * NVOX;
    float* db = data + (size_t)b * CHANS * NVOX + v0;
    #pragma unroll
    for (int c = 0; c < CHANS; ++c) {
        nt_float2 o = {m[0][c], m[1][c]};
        __builtin_nontemporal_store(o, (nt_float2*)(db + (size_t)c * NVOX));
    }
}

// ============================== fallback path (round-1) ==============================

__device__ __forceinline__ unsigned flip_f32(float f) {
    unsigned u = __float_as_uint(f);
    unsigned mask = (unsigned)(-(int)(u >> 31)) | 0x80000000u;
    return u ^ mask;
}
__device__ __forceinline__ float unflip_f32(unsigned u) {
    unsigned mask = ((u >> 31) - 1u) | 0x80000000u;
    return __uint_as_float(u ^ mask);
}
#define FLIP_NEG_INF 0x007FFFFFu

__global__ void pv_init(uint4* __restrict__ out) {
    const int DATA4 = BATCH * CHANS * NVOX / 4;
    const int TOT4  = BATCH * (CHANS + 1) * NVOX / 4;
    int i = blockIdx.x * blockDim.x + threadIdx.x;
    if (i < TOT4) {
        unsigned val = (i < DATA4) ? FLIP_NEG_INF : 0u;
        out[i] = uint4{val, val, val, val};
    }
}

__global__ void pv_scatter(const float* __restrict__ coords,
                           const float* __restrict__ attrs,
                           const float* __restrict__ origin,
                           unsigned*    __restrict__ data_u,
                           unsigned*    __restrict__ cnt)
{
    int id = blockIdx.x * blockDim.x + threadIdx.x;
    if (id >= TOTPTS) return;
    int b = id / NPTS;
    int n = id - b * NPTS;
    const float* cb = coords + (size_t)b * 3 * NPTS;
    float x = cb[n], y = cb[NPTS + n], z = cb[2 * NPTS + n];
    float ox = origin[b * 3 + 0], oy = origin[b * 3 + 1], oz = origin[b * 3 + 2];
    int ix = (int)floorf((x - ox) / VOXEL_SIZE);
    int iy = (int)floorf((y - oy) / VOXEL_SIZE);
    int iz = (int)floorf((z - oz) / VOXEL_SIZE);
    if ((unsigned)ix < GRID_W && (unsigned)iy < GRID_L && (unsigned)iz < GRID_H) {
        int flat = ix * (GRID_L * GRID_H) + iy * GRID_H + iz;
        atomicAdd(&cnt[b * NVOX + flat], 1u);
        const float* ab = attrs + (size_t)b * CHANS * NPTS + n;
        unsigned*    db = data_u + (size_t)b * CHANS * NVOX + flat;
        #pragma unroll
        for (int c = 0; c < CHANS; ++c)
            atomicMax(&db[(size_t)c * NVOX], flip_f32(ab[(size_t)c * NPTS]));
    }
}

__global__ void pv_finalize(unsigned* __restrict__ data_u,
                            unsigned* __restrict__ cnt_u)
{
    int id = blockIdx.x * blockDim.x + threadIdx.x;
    if (id >= TOTVOX) return;
    int b = id / NVOX;
    int v = id - b * NVOX;
    unsigned cnt = cnt_u[id];
    bool occ = (cnt >= MIN_PTS);
    ((float*)cnt_u)[id] = occ ? 1.0f : 0.0f;
    unsigned* db = data_u + (size_t)b * CHANS * NVOX + v;
    #pragma unroll
    for (int c = 0; c < CHANS; ++c) {
        float f = unflip_f32(db[(size_t)c * NVOX]);
        ((float*)db)[(size_t)c * NVOX] = (occ && isfinite(f)) ? f : 0.0f;
    }
}

// ============================== launch ==============================

extern "C" void kernel_launch(void* const* d_in, const int* in_sizes, int n_in,
                              void* d_out, int out_size, void* d_ws, size_t ws_size,
                              hipStream_t stream) {
    const float* coords = (const float*)d_in[0];  // [4,3,480,640]
    const float* attrs  = (const float*)d_in[1];  // [4,16,480,640]
    const float* origin = (const float*)d_in[2];  // [4,3]

    float* out = (float*)d_out;
    float* data = out;                                          // [B,C,NVOX]
    float* occ  = out + (size_t)BATCH * CHANS * NVOX;           // [B,NVOX]

    if (ws_size >= WS_NEEDED) {
        char* ws = (char*)d_ws;
        unsigned* offsets = (unsigned*)(ws + WS_OFFSETS);  // counts -> offsets (in-place)
        unsigned* vr      = (unsigned*)(ws + WS_VR);
        int*      ids     = (int*)(ws + WS_IDS);
        unsigned* rows    = (unsigned*)(ws + WS_ROWS);
        unsigned* sums    = (unsigned*)(ws + WS_SUMS);

        // zero counts + the 4 sentinel words past the end
        (void)hipMemsetAsync(offsets, 0, (size_t)(TOTVOX + 4) * 4, stream);
        k_hist_pack<<<(TOTPTS / 2 + 255) / 256, 256, 0, stream>>>(coords, attrs, origin,
                                                                  vr, rows, offsets);
        k_scan1<<<SCAN_BLKS, SCAN_TPB, 0, stream>>>(offsets, sums, occ);
        k_scan2<<<1, 1024, 0, stream>>>(sums);
        k_scatter_ids4<<<(TOTPTS / 4 + 255) / 256, 256, 0, stream>>>(vr, offsets, sums, ids);
        k_gather_ind2<<<(TOTVOX / 2 + 255) / 256, 256, 0, stream>>>(rows, ids, offsets, sums, data);
    } else {
        unsigned* data_u = (unsigned*)data;
        unsigned* cnt    = (unsigned*)occ;
        const int TOT4 = BATCH * (CHANS + 1) * NVOX / 4;
        pv_init<<<(TOT4 + 255) / 256, 256, 0, stream>>>((uint4*)d_out);
        pv_scatter<<<(TOTPTS + 255) / 256, 256, 0, stream>>>(coords, attrs, origin, data_u, cnt);
        pv_finalize<<<(TOTVOX + 255) / 256, 256, 0, stream>>>(data_u, cnt);
    }
}